// Round 6
// baseline (236.450 us; speedup 1.0000x reference)
//
#include <hip/hip_runtime.h>
#include <hip/hip_fp16.h>
#include <stdint.h>

// Problem constants (from reference setup_inputs)
#define BATCH 256
#define PSEL  128
#define IN_DIM 3200
#define O1_DIM 8192
#define O3_DIM 4096

// ---------------------------------------------------------------------------
// transpose x [256, 3200] fp32 -> xT [3200, 256] fp16
// Fused: out = -8.0 (final bias; atomics accumulate on top) and
// stats accumulators (4 x 256 floats) = 0.
// ---------------------------------------------------------------------------
__global__ __launch_bounds__(256) void transpose_kernel(const float* __restrict__ x,
                                                        __half* __restrict__ xT,
                                                        float* __restrict__ out,
                                                        float* __restrict__ stats) {
    int tx = threadIdx.x;       // 32
    int ty = threadIdx.y;       // 8
    int tid = ty * 32 + tx;
    int gid = blockIdx.y * gridDim.x + blockIdx.x;   // 0..799
    if (gid < 256) out[gid * 256 + tid] = -8.0f;
    else if (gid < 260) stats[(gid - 256) * 256 + tid] = 0.0f;

    __shared__ float tile[32][33];
    int i0 = blockIdx.x * 32;   // input-dim tile (3200/32 = 100)
    int b0 = blockIdx.y * 32;   // batch tile    (256/32 = 8)
#pragma unroll
    for (int k = 0; k < 4; ++k)
        tile[ty + k * 8][tx] = x[(size_t)(b0 + ty + k * 8) * IN_DIM + i0 + tx];
    __syncthreads();
#pragma unroll
    for (int k = 0; k < 4; ++k)
        xT[(size_t)(i0 + ty + k * 8) * BATCH + b0 + tx] =
            __float2half(tile[tx][ty + k * 8]);
}

// ---------------------------------------------------------------------------
// stats: per-batch-column sum and sum-of-squares of hT [N, 256] (fp16 in, fp32 acc)
// grid = 256 blocks, each handles N/256 contiguous rows; coalesced reads.
// ---------------------------------------------------------------------------
__global__ __launch_bounds__(256) void stats_kernel(const __half* __restrict__ hT,
                                                    float* __restrict__ gsum,
                                                    float* __restrict__ gsq,
                                                    int rows_per_block) {
    int t = threadIdx.x;
    const __half* p = hT + (size_t)blockIdx.x * rows_per_block * BATCH + t;
    float s = 0.0f, q = 0.0f;
    for (int r = 0; r < rows_per_block; ++r) {
        float v = __half2float(p[(size_t)r * BATCH]);
        s += v;
        q = fmaf(v, v, q);
    }
    atomicAdd(&gsum[t], s);
    atomicAdd(&gsq[t], q);
}

// ---------------------------------------------------------------------------
// popcnt layer: one block (256 threads) per TWO outputs.
// Threads 0-127 own output o0, threads 128-255 own o1. Each thread owns one
// batch-dword (2 fp16 elems) and runs the FULL 128-iteration gather chain:
// complete sums in registers, no cross-thread reduction, no post-loop barrier
// (R1's proven high-occupancy structure, 42.6 lines/cy). Wave loads are thin
// 256 B (2 L2 lines) with the row address LDS-broadcast per iteration.
// Layernorm of the INPUT folded algebraically:
//   sum_p w_p*((v-mu)*rs*g_p + be_p) = rs*acc + sumC - rs*mu*sumA
// FINAL: atomicAdd sigmoid into out[b*256 + o/16] (pre-init'd to -8).
// ---------------------------------------------------------------------------
template <bool NORM, bool FINAL>
__global__ __launch_bounds__(256) void popcnt_kernel(
    const __half* __restrict__ actT,  // [Nin, 256] fp16, rows = 512 B
    const int* __restrict__ sel,      // [Nout, 128]
    const float* __restrict__ w,      // [Nout, 128]
    const float* __restrict__ bias,   // [Nout]
    const float* __restrict__ g,      // [Nin]  (NORM only)
    const float* __restrict__ be,     // [Nin]  (NORM only)
    const float* __restrict__ gsum,   // [256]  (NORM only)
    const float* __restrict__ gsq,    // [256]  (NORM only)
    float inv_n,                      // 1/Nin  (NORM only)
    void* __restrict__ outp)          // fp16 [Nout,256] or final fp32 [256,256]
{
    const int t    = threadIdx.x;     // 0..255
    const int half = t >> 7;          // which of the block's 2 outputs
    const int col  = t & 127;         // batch dword (batch elems 2col, 2col+1)
    const int o    = blockIdx.x * 2 + half;

    __shared__ alignas(16) uint32_t s_pair[2][2 * PSEL];  // {byte_offset, A_p}
    __shared__ float s_rA[2][PSEL], s_rC[2][PSEL];
    __shared__ float s_sums[2][2];

    // ---- prologue: 128 threads per output load its sel/w ----
    {
        int idx  = __builtin_nontemporal_load(&sel[o * PSEL + col]);
        float ww = __builtin_nontemporal_load(&w[o * PSEL + col]);
        float sw = 1.0f / (1.0f + __expf(-ww));   // resilu(w) == sigmoid(w)
        float a, c;
        if (NORM) { a = sw * g[idx]; c = sw * be[idx]; }
        else      { a = sw;          c = 0.0f; }
        s_pair[half][2 * col]     = (uint32_t)idx << 9;   // idx * 256 halves * 2B
        s_pair[half][2 * col + 1] = __float_as_uint(a);
        if (NORM) { s_rA[half][col] = a; s_rC[half][col] = c; }
    }
    __syncthreads();

    if (NORM && (t & 64) == 0) {      // wave 0 -> output 0, wave 2 -> output 1
        int l = t & 63;
        float va = s_rA[half][l] + s_rA[half][l + 64];
        float vc = s_rC[half][l] + s_rC[half][l + 64];
#pragma unroll
        for (int off = 32; off > 0; off >>= 1) {
            va += __shfl_xor(va, off, 64);
            vc += __shfl_xor(vc, off, 64);
        }
        if (l == 0) { s_sums[half][0] = va; s_sums[half][1] = vc; }
    }

    // ---- gather: 128 thin dword loads per thread, uninterrupted chain ----
    const uint2* pairs = (const uint2*)s_pair[half];
    const char* base = (const char*)actT + (uint32_t)(col * 4);
    float acc0 = 0.0f, acc1 = 0.0f;
#pragma unroll 16
    for (int i = 0; i < PSEL; ++i) {
        uint2 pr = pairs[i];                        // LDS broadcast per wave
        uint32_t d = *(const uint32_t*)(base + pr.x);
        float A = __uint_as_float(pr.y);
        float2 f = __half22float2(*(const __half2*)&d);
        acc0 = fmaf(A, f.x, acc0);
        acc1 = fmaf(A, f.y, acc1);
    }

    if (NORM) __syncthreads();        // publish s_sums (waves converge anyway)

    // ---- epilogue: every thread finishes its own 2 batch elements ----
    float z0, z1;
    float bo = bias[o];
    if (NORM) {
        float2 ms = ((const float2*)gsum)[col];
        float2 qs = ((const float2*)gsq)[col];
        float m0 = ms.x * inv_n, m1 = ms.y * inv_n;
        float q0 = qs.x * inv_n, q1 = qs.y * inv_n;
        float rs0 = rsqrtf(q0 - m0 * m0 + 1e-12f);
        float rs1 = rsqrtf(q1 - m1 * m1 + 1e-12f);
        float sA = s_sums[half][0], sC = s_sums[half][1];
        z0 = rs0 * acc0 + sC - rs0 * m0 * sA - bo;
        z1 = rs1 * acc1 + sC - rs1 * m1 * sA - bo;
    } else {
        z0 = acc0 - bo;
        z1 = acc1 - bo;
    }
    float h0 = 1.0f / (1.0f + __expf(-z0));
    float h1 = 1.0f / (1.0f + __expf(-z1));

    if (FINAL) {
        float* out = (float*)outp;
        int grp = o >> 4;
        atomicAdd(&out[(2 * col) * 256 + grp], h0);
        atomicAdd(&out[(2 * col + 1) * 256 + grp], h1);
    } else {
        __half2 hv = __floats2half2_rn(h0, h1);
        *(__half2*)((__half*)outp + (size_t)o * BATCH + 2 * col) = hv;
    }
}

// ---------------------------------------------------------------------------
extern "C" void kernel_launch(void* const* d_in, const int* in_sizes, int n_in,
                              void* d_out, int out_size, void* d_ws, size_t ws_size,
                              hipStream_t stream) {
    const float* x    = (const float*)d_in[0];
    const int*   sel1 = (const int*)d_in[1];
    const float* w1   = (const float*)d_in[2];
    const float* b1   = (const float*)d_in[3];
    const float* g1   = (const float*)d_in[4];
    const float* be1  = (const float*)d_in[5];
    const int*   sel2 = (const int*)d_in[6];
    const float* w2   = (const float*)d_in[7];
    const float* b2   = (const float*)d_in[8];
    const float* g2   = (const float*)d_in[9];
    const float* be2  = (const float*)d_in[10];
    const int*   sel3 = (const int*)d_in[11];
    const float* w3   = (const float*)d_in[12];
    const float* b3   = (const float*)d_in[13];
    float* out = (float*)d_out;

    // workspace layout (fp16 activations)
    char* ws = (char*)d_ws;
    __half* xT  = (__half*)(ws);                          // 3200*256*2 = 1,638,400
    __half* h1T = (__half*)(ws + 1638400);                // 8192*256*2 = 4,194,304
    __half* h2T = (__half*)(ws + 1638400 + 4194304);      // 4,194,304
    float* stats = (float*)(ws + 1638400 + 2 * 4194304);  // 4 * 256 floats
    float* gs1 = stats;
    float* gq1 = stats + 256;
    float* gs2 = stats + 512;
    float* gq2 = stats + 768;

    // transpose + init(out, stats) fused
    transpose_kernel<<<dim3(IN_DIM / 32, BATCH / 32), dim3(32, 8), 0, stream>>>(
        x, xT, out, stats);

    // Layer 1: x -> h1 (no input norm)
    popcnt_kernel<false, false><<<O1_DIM / 2, 256, 0, stream>>>(
        xT, sel1, w1, b1, nullptr, nullptr, nullptr, nullptr, 0.0f, h1T);

    // stats of h1 for layernorm 1
    stats_kernel<<<256, 256, 0, stream>>>(h1T, gs1, gq1, O1_DIM / 256);

    // Layer 2: layernorm(h1) folded in
    popcnt_kernel<true, false><<<O1_DIM / 2, 256, 0, stream>>>(
        h1T, sel2, w2, b2, g1, be1, gs1, gq1, 1.0f / (float)O1_DIM, h2T);

    // stats of h2 for layernorm 2
    stats_kernel<<<256, 256, 0, stream>>>(h2T, gs2, gq2, O1_DIM / 256);

    // Layer 3: layernorm(h2) folded in, final group-sum via atomics into out
    popcnt_kernel<true, true><<<O3_DIM / 2, 256, 0, stream>>>(
        h2T, sel3, w3, b3, g2, be2, gs2, gq2, 1.0f / (float)O1_DIM, out);
}